// Round 8
// baseline (25.395 us; speedup 1.0000x reference)
//
#include <hip/hip_runtime.h>

// Lucas-Kanade optical flow — r8: 2x4 output patch per thread (TH=64).
// LDS reads 13.5 -> 9 per px, product muls 22.5 -> 15 per px, Phase-B setup
// amortized over 8 px. Op/rounding order per pixel identical to r7 (verified
// absmax 0.0078125, 73x under threshold).
// Input:  image_prev, image_next  (1,1,2048,2048) fp32
// Output: (1,2,2048,2048) fp32  -> u at [0:H*W], v at [H*W:2*H*W]

#pragma clang fp contract(off)

#define IMG_H 2048
#define IMG_W 2048
#define TW 32
#define TH 64
// LDS col c holds res at image col (c0 + c - 1): 0 = left halo, 1..32 interior,
// 33 = right halo, 34 = pad. stride 35 (odd) -> bank = 3*row + col: 2-way, free.
#define LDSW 35

__global__ __launch_bounds__(256, 4)
void lk_flow_v8(const float* __restrict__ prev,
                const float* __restrict__ next,
                float* __restrict__ out) {
    #pragma clang fp contract(off)
    __shared__ float srx[(TH + 2) * LDSW];
    __shared__ float sry[(TH + 2) * LDSW];
    __shared__ float srt[(TH + 2) * LDSW];

    // XCD-aware remap: 2048 blocks, 256 per XCD = 4 contiguous tile-rows of 64.
    const int lin = (int)blockIdx.y * (int)gridDim.x + (int)blockIdx.x;
    const int nl  = (lin >> 3) + (lin & 7) * 256;
    const int r0  = (nl >> 6) * TH;
    const int c0  = (nl & 63) * TW;

    const int tx  = (int)threadIdx.x;   // 0..7
    const int ty  = (int)threadIdx.y;   // 0..31
    const int tid = ty * 8 + tx;

    // rows touched: r0-1 .. r0+TH+1 (incl. a1); cols touched: c0-1 .. c0+TW+1
    const bool interior = (r0 > 0) & (r0 + TH + 2 <= IMG_H - 1) &
                          (c0 > 0) & (c0 + TW + 2 <= IMG_W - 1);

    if (interior) {
        // ---- fast Phase A: no bounds checks, no reflect, int32 addressing ----
        // (TH+2)*8 = 528 chunks: 2 full passes + 16
        #pragma unroll
        for (int pass = 0; pass < 3; ++pass) {
            const int t = tid + pass * 256;
            if (pass < 2 || tid < 16) {
                const int hr = t >> 3;
                const int ch = t & 7;
                const int i0 = (r0 - 1 + hr) * IMG_W + (c0 + ch * 4);
                const int i1 = i0 + IMG_W;
                const float4 P0 = *reinterpret_cast<const float4*>(prev + i0);
                const float4 P1 = *reinterpret_cast<const float4*>(prev + i1);
                const float4 Q0 = *reinterpret_cast<const float4*>(next + i0);
                const float4 Q1 = *reinterpret_cast<const float4*>(next + i1);
                const float p0[5] = {P0.x, P0.y, P0.z, P0.w, prev[i0 + 4]};
                const float p1[5] = {P1.x, P1.y, P1.z, P1.w, prev[i1 + 4]};
                const float q0[5] = {Q0.x, Q0.y, Q0.z, Q0.w, next[i0 + 4]};
                const float q1[5] = {Q1.x, Q1.y, Q1.z, Q1.w, next[i1 + 4]};
                const int base = hr * LDSW + 1 + ch * 4;
                #pragma unroll
                for (int k = 0; k < 4; ++k) {
                    // bit-equal to reference left-to-right order:
                    //   gx=((p01-p00)-p10)+p11; gy=(p10-(p00+p01))+p11; gs=((p00+p01)+p10)+p11
                    const float Ap = p0[k] + p0[k + 1];
                    const float Aq = q0[k] + q0[k + 1];
                    const float gxp = ((p0[k + 1] - p0[k]) - p1[k]) + p1[k + 1];
                    const float gxq = ((q0[k + 1] - q0[k]) - q1[k]) + q1[k + 1];
                    const float gyp = (p1[k] - Ap) + p1[k + 1];
                    const float gyq = (q1[k] - Aq) + q1[k + 1];
                    const float gsp = (Ap + p1[k]) + p1[k + 1];
                    const float gsq = (Aq + q1[k]) + q1[k + 1];
                    srx[base + k] = 0.5f * (gxp + gxq);
                    sry[base + k] = 0.5f * (gyp + gyq);
                    srt[base + k] = 0.5f * (gsq - gsp);     // 0.5*(-gsp+gsq)
                }
            }
        }
        if (tid < (TH + 2) * 2) {   // 132 edge cells: e=0 -> c0-1 (LDS 0), e=1 -> c0+32 (LDS 33)
            const int hr = tid >> 1;
            const int e  = tid & 1;
            const int bc = e ? (c0 + TW) : (c0 - 1);
            const int i0 = (r0 - 1 + hr) * IMG_W + bc;
            const int i1 = i0 + IMG_W;
            const float p00 = prev[i0], p01 = prev[i0 + 1];
            const float p10 = prev[i1], p11 = prev[i1 + 1];
            const float q00 = next[i0], q01 = next[i0 + 1];
            const float q10 = next[i1], q11 = next[i1 + 1];
            const float Ap = p00 + p01, Aq = q00 + q01;
            const float gxp = ((p01 - p00) - p10) + p11;
            const float gxq = ((q01 - q00) - q10) + q11;
            const float gyp = (p10 - Ap) + p11;
            const float gyq = (q10 - Aq) + q11;
            const float gsp = (Ap + p10) + p11;
            const float gsq = (Aq + q10) + q11;
            const int o = hr * LDSW + (e ? 33 : 0);
            srx[o] = 0.5f * (gxp + gxq);
            sry[o] = 0.5f * (gyp + gyq);
            srt[o] = 0.5f * (gsq - gsp);
        }
    } else {
        // ---- slow Phase A: full bounds + reflect, scalar per LDS cell ----
        for (int t = tid; t < (TH + 2) * 34; t += 256) {
            const int hr = t / 34;
            const int c  = t - hr * 34;
            const int a  = r0 - 1 + hr;
            const int bc = c0 - 1 + c;
            float rx = 0.f, ry = 0.f, rt = 0.f;
            if (a >= 0 && a < IMG_H && bc >= 0 && bc < IMG_W) {
                const int a1 = (a + 1 == IMG_H) ? (IMG_H - 2) : (a + 1);   // reflect (after)
                const int b1 = (bc + 1 == IMG_W) ? (IMG_W - 2) : (bc + 1); // reflect (after)
                const int i0 = a * IMG_W, i1 = a1 * IMG_W;
                const float p00 = prev[i0 + bc], p01 = prev[i0 + b1];
                const float p10 = prev[i1 + bc], p11 = prev[i1 + b1];
                const float q00 = next[i0 + bc], q01 = next[i0 + b1];
                const float q10 = next[i1 + bc], q11 = next[i1 + b1];
                const float Ap = p00 + p01, Aq = q00 + q01;
                const float gxp = ((p01 - p00) - p10) + p11;
                const float gxq = ((q01 - q00) - q10) + q11;
                const float gyp = (p10 - Ap) + p11;
                const float gyq = (q10 - Aq) + q11;
                const float gsp = (Ap + p10) + p11;
                const float gsq = (Aq + q10) + q11;
                rx = 0.5f * (gxp + gxq);
                ry = 0.5f * (gyp + gyq);
                rt = 0.5f * (gsq - gsp);
            }
            const int o = hr * LDSW + c;
            srx[o] = rx; sry[o] = ry; srt[o] = rt;
        }
    }

    __syncthreads();

    // ---- Phase B: each thread -> 2 output rows x 4 output cols ----
    // output rows (local) 2ty, 2ty+1; res LDS rows 2ty..2ty+3; LDS cols 4tx..4tx+5.
    const int jb = tx * 4;
    int off = (ty * 2) * LDSW + jb;

    // acc[o][q][s], s: 0=Sxx 1=Syy 2=Sxy 3=Sxt 4=Syt
    float aXX[2][4] = {}, aYY[2][4] = {}, aXY[2][4] = {}, aXT[2][4] = {}, aYT[2][4] = {};

    #pragma unroll
    for (int ld = 0; ld < 4; ++ld) {
        const float* px = srx + off;
        const float* py = sry + off;
        const float* pt = srt + off;
        float X[6], Y[6], T[6];
        #pragma unroll
        for (int k = 0; k < 6; ++k) { X[k] = px[k]; Y[k] = py[k]; T[k] = pt[k]; }
        off += LDSW;
        float xx[6], yy[6], xy[6], xt[6], yt[6];
        #pragma unroll
        for (int k = 0; k < 6; ++k) {
            xx[k] = X[k] * X[k];
            yy[k] = Y[k] * Y[k];
            xy[k] = X[k] * Y[k];
            xt[k] = T[k] * X[k];
            yt[k] = T[k] * Y[k];
        }
        // res row ld feeds output row o=0 as dr=ld (ld<=2) and o=1 as dr=ld-1 (ld>=1).
        // Per-acc chain order stays: dr ascending (ld asc), dc inner ascending.
        #pragma unroll
        for (int o = 0; o < 2; ++o) {
            if (ld >= o && ld <= o + 2) {   // compile-time after unroll
                #pragma unroll
                for (int q = 0; q < 4; ++q) {
                    aXX[o][q] += xx[q]; aXX[o][q] += xx[q + 1]; aXX[o][q] += xx[q + 2];
                    aYY[o][q] += yy[q]; aYY[o][q] += yy[q + 1]; aYY[o][q] += yy[q + 2];
                    aXY[o][q] += xy[q]; aXY[o][q] += xy[q + 1]; aXY[o][q] += xy[q + 2];
                    aXT[o][q] += xt[q]; aXT[o][q] += xt[q + 1]; aXT[o][q] += xt[q + 2];
                    aYT[o][q] += yt[q]; aYT[o][q] += yt[q + 1]; aYT[o][q] += yt[q + 2];
                }
            }
        }
    }

    #pragma unroll
    for (int o = 0; o < 2; ++o) {
        const int i = r0 + ty * 2 + o;
        float uo[4], vo[4];
        #pragma unroll
        for (int q = 0; q < 4; ++q) {
            const float Sxx = aXX[o][q], Syy = aYY[o][q], Sxy = aXY[o][q];
            const float Sxt = aXT[o][q], Syt = aYT[o][q];
            const float t1 = Sxx * Syy;
            const float t2 = Sxy * Sxy;
            const float det = t1 - t2;
            float u = 0.f, v = 0.f;
            if (det != 0.f) {
                const float inv = __builtin_amdgcn_rcpf(det);  // 1-ulp rcp, ample margin
                const float n1 = Syy * Sxt - Sxy * Syt;
                const float n2 = Sxx * Syt - Sxy * Sxt;
                u = n1 * inv;
                v = n2 * inv;
            }
            const int j = c0 + jb + q;
            if (i == 0 || j == 0) { u = 0.f; v = 0.f; }  // reference zeroes row0/col0
            uo[q] = u; vo[q] = v;
        }
        const int oidx = i * IMG_W + (c0 + jb);
        float4 U = {uo[0], uo[1], uo[2], uo[3]};
        float4 V = {vo[0], vo[1], vo[2], vo[3]};
        *reinterpret_cast<float4*>(out + oidx) = U;
        *reinterpret_cast<float4*>(out + IMG_H * IMG_W + oidx) = V;
    }
}

extern "C" void kernel_launch(void* const* d_in, const int* in_sizes, int n_in,
                              void* d_out, int out_size, void* d_ws, size_t ws_size,
                              hipStream_t stream) {
    const float* prev = (const float*)d_in[0];
    const float* next = (const float*)d_in[1];
    float* out = (float*)d_out;
    dim3 grid(IMG_W / TW, IMG_H / TH);   // 64 x 32
    dim3 block(8, 32);
    lk_flow_v8<<<grid, block, 0, stream>>>(prev, next, out);
}